// Round 1
// baseline (382.843 us; speedup 1.0000x reference)
//
#include <hip/hip_runtime.h>

// One block per row. S = 8192, 256 threads * 8 int4 loads = 8192 int32/row.
__global__ __launch_bounds__(256) void row_check_kernel(
    const int* __restrict__ x, int* __restrict__ out, int S) {
  const int row = blockIdx.x;
  const size_t rowoff = (size_t)row * (size_t)S;
  const int4* rp = (const int4*)(x + rowoff);
  const int t = threadIdx.x;

  unsigned pres = 0;   // bit v set if token v present (clipped to [0,7])
  int last1 = -1;      // max position where token == 1
  int rg12 = 0;        // only meaningful on thread 0

  #pragma unroll
  for (int k = 0; k < 8; ++k) {
    const int c = t + (k << 8);      // int4 chunk index, coalesced per wave
    const int4 v = rp[c];
    const int base = c << 2;         // element index of v.x
    const int e0 = v.x, e1 = v.y, e2 = v.z, e3 = v.w;
    // presence uses clipped values (ref: jnp.clip(vals, 0, 7))
    const int c0 = min(max(e0, 0), 7), c1 = min(max(e1, 0), 7);
    const int c2 = min(max(e2, 0), 7), c3 = min(max(e3, 0), 7);
    pres |= (1u << c0) | (1u << c1) | (1u << c2) | (1u << c3);
    // last occurrence of raw token 1: k ascends, so later finds overwrite
    if (e3 == 1)      last1 = base + 3;
    else if (e2 == 1) last1 = base + 2;
    else if (e1 == 1) last1 = base + 1;
    else if (e0 == 1) last1 = base;
    if (k == 0 && t == 0) {
      // rg1: first token != 0 -> +4 ; rg2: second token != 1 -> +4
      rg12 = ((e0 != 0) ? 4 : 0) + ((e1 != 1) ? 4 : 0);
    }
  }

  // wave(64)-level reduce: OR for presence, max for last1
  #pragma unroll
  for (int off = 32; off > 0; off >>= 1) {
    pres |= (unsigned)__shfl_down((int)pres, off);
    last1 = max(last1, __shfl_down(last1, off));
  }

  __shared__ unsigned spres[4];
  __shared__ int slast[4];
  const int wave = t >> 6;
  if ((t & 63) == 0) { spres[wave] = pres; slast[wave] = last1; }
  __syncthreads();

  if (t == 0) {
    const unsigned p = spres[0] | spres[1] | spres[2] | spres[3];
    const int l1 = max(max(slast[0], slast[1]), max(slast[2], slast[3]));
    const int d = 8 - __popc(p);
    const int rg3 = d * d;
    int rg4;
    if (l1 > 0 && l1 < S - 5) {
      // gather 5 following tokens; row was just streamed -> cache-hot
      const int* r = x + rowoff + l1;
      rg4 = (int)(r[1] != 2) + (int)(r[2] != 4) + (int)(r[3] != 5) +
            (int)(r[4] != 6) + (int)(r[5] != 3);
    } else {
      rg4 = 6;  // covers last1 == -1 (no token 1), last1 == 0, last1 >= S-5
    }
    atomicAdd(out, rg12 + rg3 + rg4);
  }
}

extern "C" void kernel_launch(void* const* d_in, const int* in_sizes, int n_in,
                              void* d_out, int out_size, void* d_ws, size_t ws_size,
                              hipStream_t stream) {
  const int* x = (const int*)d_in[0];
  const int S = 8192;
  const int B = in_sizes[0] / S;   // 8192
  int* out = (int*)d_out;
  // d_out is re-poisoned to 0xAA before every timed replay -> zero it on-stream
  hipMemsetAsync(out, 0, sizeof(int) * (size_t)out_size, stream);
  row_check_kernel<<<dim3(B), dim3(256), 0, stream>>>(x, out, S);
}

// Round 2
// 357.271 us; speedup vs baseline: 1.0716x; 1.0716x over previous
//
#include <hip/hip_runtime.h>

// Stage 1: one block per row. S = 8192, 256 threads * 8 int4 loads = 8192 int32/row.
// Writes one partial sum per row into ws[row] (no atomics -> no cross-XCD
// single-address serialization).
__global__ __launch_bounds__(256) void row_check_kernel(
    const int* __restrict__ x, int* __restrict__ partial, int S) {
  const int row = blockIdx.x;
  const size_t rowoff = (size_t)row * (size_t)S;
  const int4* rp = (const int4*)(x + rowoff);
  const int t = threadIdx.x;

  unsigned pres = 0;   // bit v set if token v present (clipped to [0,7])
  int last1 = -1;      // max position where token == 1
  int rg12 = 0;        // only meaningful on thread 0

  #pragma unroll
  for (int k = 0; k < 8; ++k) {
    const int c = t + (k << 8);      // int4 chunk index, coalesced per wave
    const int4 v = rp[c];
    const int base = c << 2;         // element index of v.x
    const int e0 = v.x, e1 = v.y, e2 = v.z, e3 = v.w;
    // presence uses clipped values (ref: jnp.clip(vals, 0, 7))
    const int c0 = min(max(e0, 0), 7), c1 = min(max(e1, 0), 7);
    const int c2 = min(max(e2, 0), 7), c3 = min(max(e3, 0), 7);
    pres |= (1u << c0) | (1u << c1) | (1u << c2) | (1u << c3);
    // last occurrence of raw token 1 (branch-free: cndmask + max)
    last1 = max(last1, (e0 == 1) ? (base + 0) : -1);
    last1 = max(last1, (e1 == 1) ? (base + 1) : -1);
    last1 = max(last1, (e2 == 1) ? (base + 2) : -1);
    last1 = max(last1, (e3 == 1) ? (base + 3) : -1);
    if (k == 0 && t == 0) {
      // rg1: first token != 0 -> +4 ; rg2: second token != 1 -> +4
      rg12 = ((e0 != 0) ? 4 : 0) + ((e1 != 1) ? 4 : 0);
    }
  }

  // wave(64)-level reduce: OR for presence, max for last1
  #pragma unroll
  for (int off = 32; off > 0; off >>= 1) {
    pres |= (unsigned)__shfl_down((int)pres, off);
    last1 = max(last1, __shfl_down(last1, off));
  }

  __shared__ unsigned spres[4];
  __shared__ int slast[4];
  const int wave = t >> 6;
  if ((t & 63) == 0) { spres[wave] = pres; slast[wave] = last1; }
  __syncthreads();

  if (t == 0) {
    const unsigned p = spres[0] | spres[1] | spres[2] | spres[3];
    const int l1 = max(max(slast[0], slast[1]), max(slast[2], slast[3]));
    const int d = 8 - __popc(p);
    const int rg3 = d * d;
    int rg4;
    if (l1 > 0 && l1 < S - 5) {
      // gather 5 following tokens; row was just streamed -> L2-hot
      const int* r = x + rowoff + l1;
      rg4 = (int)(r[1] != 2) + (int)(r[2] != 4) + (int)(r[3] != 5) +
            (int)(r[4] != 6) + (int)(r[5] != 3);
    } else {
      rg4 = 6;  // covers last1 == -1 (no token 1), last1 == 0, last1 >= S-5
    }
    partial[row] = rg12 + rg3 + rg4;   // plain store, no atomic
  }
}

// Stage 2: single block sums B partials (B = 8192 -> 32 per thread) and
// writes the scalar result directly (d_out needs no pre-zeroing).
__global__ __launch_bounds__(256) void final_reduce_kernel(
    const int* __restrict__ partial, int* __restrict__ out, int B) {
  const int t = threadIdx.x;
  int s = 0;
  for (int i = t; i < B; i += 256) s += partial[i];
  #pragma unroll
  for (int off = 32; off > 0; off >>= 1) s += __shfl_down(s, off);
  __shared__ int sw[4];
  if ((t & 63) == 0) sw[t >> 6] = s;
  __syncthreads();
  if (t == 0) out[0] = sw[0] + sw[1] + sw[2] + sw[3];
}

extern "C" void kernel_launch(void* const* d_in, const int* in_sizes, int n_in,
                              void* d_out, int out_size, void* d_ws, size_t ws_size,
                              hipStream_t stream) {
  const int* x = (const int*)d_in[0];
  const int S = 8192;
  const int B = in_sizes[0] / S;   // 8192
  int* partial = (int*)d_ws;       // B ints, fully overwritten each call
  int* out = (int*)d_out;
  row_check_kernel<<<dim3(B), dim3(256), 0, stream>>>(x, partial, S);
  final_reduce_kernel<<<dim3(1), dim3(256), 0, stream>>>(partial, out, B);
}

// Round 3
// 354.260 us; speedup vs baseline: 1.0807x; 1.0085x over previous
//
#include <hip/hip_runtime.h>

// Stage 1: one WAVE per row (no LDS, no __syncthreads).
// Block = 256 threads = 4 waves = 4 rows; grid = B/4 = 2048 blocks.
// Each lane loads 32 int4 (row = 64 lanes * 32 * 4 = 8192 int32), software-
// pipelined in 4 groups of 8 with 2-deep prefetch to keep 8 dwordx4 loads
// in flight per lane without blowing VGPRs (~84 -> 6 waves/SIMD).
__global__ __launch_bounds__(256) void row_check_kernel(
    const int* __restrict__ x, int* __restrict__ partial) {
  const int wave = threadIdx.x >> 6;
  const int lane = threadIdx.x & 63;
  const int row  = (blockIdx.x << 2) + wave;
  const size_t rowoff = (size_t)row << 13;            // row * 8192
  const int4* rp = (const int4*)(x + rowoff);         // 2048 int4 per row

  unsigned pres = 0;   // bit v set if token v present (clipped to [0,7])
  int last1 = -1;      // max element index where token == 1
  int rg12 = 0;        // lane 0 only: first-token/second-token penalties

  int4 buf[8];
  #pragma unroll
  for (int j = 0; j < 8; ++j) buf[j] = rp[lane + (j << 6)];

  #pragma unroll
  for (int g = 0; g < 4; ++g) {
    int4 nxt[8];
    if (g < 3) {
      #pragma unroll
      for (int j = 0; j < 8; ++j) nxt[j] = rp[lane + (((g + 1) * 8 + j) << 6)];
    }
    #pragma unroll
    for (int j = 0; j < 8; ++j) {
      const int4 v = buf[j];
      const int base = (lane + ((g * 8 + j) << 6)) << 2;  // element idx of v.x
      const int e0 = v.x, e1 = v.y, e2 = v.z, e3 = v.w;
      // presence uses clipped values (ref: jnp.clip(vals, 0, 7)) -> v_med3
      const int c0 = min(max(e0, 0), 7), c1 = min(max(e1, 0), 7);
      const int c2 = min(max(e2, 0), 7), c3 = min(max(e3, 0), 7);
      pres |= (1u << c0) | (1u << c1) | (1u << c2) | (1u << c3);
      // last occurrence of raw token 1 (branch-free cndmask + max)
      last1 = max(last1, (e0 == 1) ? (base + 0) : -1);
      last1 = max(last1, (e1 == 1) ? (base + 1) : -1);
      last1 = max(last1, (e2 == 1) ? (base + 2) : -1);
      last1 = max(last1, (e3 == 1) ? (base + 3) : -1);
      if (g == 0 && j == 0 && lane == 0) {
        // lane 0's first int4 holds elements 0..3 of the row
        rg12 = ((e0 != 0) ? 4 : 0) + ((e1 != 1) ? 4 : 0);
      }
    }
    if (g < 3) {
      #pragma unroll
      for (int j = 0; j < 8; ++j) buf[j] = nxt[j];
    }
  }

  // wave(64) butterfly reduce: OR for presence, max for last1
  #pragma unroll
  for (int off = 32; off > 0; off >>= 1) {
    pres |= (unsigned)__shfl_down((int)pres, off);
    last1 = max(last1, __shfl_down(last1, off));
  }

  if (lane == 0) {
    const int d = 8 - __popc(pres);
    const int rg3 = d * d;
    int rg4 = 6;  // covers last1 == -1 (no token 1), last1 == 0, last1 >= S-5
    if (last1 > 0 && last1 < 8192 - 5) {
      const int* r = x + rowoff + last1;  // row just streamed -> cache-hot
      rg4 = (int)(r[1] != 2) + (int)(r[2] != 4) + (int)(r[3] != 5) +
            (int)(r[4] != 6) + (int)(r[5] != 3);
    }
    partial[row] = rg12 + rg3 + rg4;  // plain store, no atomic
  }
}

// Stage 2: single block sums B partials and writes the scalar result
// (d_out needs no pre-zeroing).
__global__ __launch_bounds__(256) void final_reduce_kernel(
    const int* __restrict__ partial, int* __restrict__ out, int B) {
  const int t = threadIdx.x;
  int s = 0;
  for (int i = t; i < B; i += 256) s += partial[i];
  #pragma unroll
  for (int off = 32; off > 0; off >>= 1) s += __shfl_down(s, off);
  __shared__ int sw[4];
  if ((t & 63) == 0) sw[t >> 6] = s;
  __syncthreads();
  if (t == 0) out[0] = sw[0] + sw[1] + sw[2] + sw[3];
}

extern "C" void kernel_launch(void* const* d_in, const int* in_sizes, int n_in,
                              void* d_out, int out_size, void* d_ws, size_t ws_size,
                              hipStream_t stream) {
  const int* x = (const int*)d_in[0];
  const int S = 8192;
  const int B = in_sizes[0] / S;   // 8192
  int* partial = (int*)d_ws;       // B ints, fully overwritten each call
  int* out = (int*)d_out;
  row_check_kernel<<<dim3(B / 4), dim3(256), 0, stream>>>(x, partial);
  final_reduce_kernel<<<dim3(1), dim3(256), 0, stream>>>(partial, out, B);
}